// Round 12
// baseline (318.132 us; speedup 1.0000x reference)
//
#include <hip/hip_runtime.h>
#include <hip/hip_bf16.h>

#define FEATSZ 2048
#define HIDSZ  1024
#define ATTSZ  512
#define BATCH  64
#define FEATN  512

typedef float  f32x4  __attribute__((ext_vector_type(4)));
typedef __bf16 bf16x8 __attribute__((ext_vector_type(8)));

__device__ __forceinline__ unsigned short f2bf(float f) {
    union { float f; unsigned int u; } x; x.f = f;
    unsigned int u = x.u;
    return (unsigned short)((u + 0x7fffu + ((u >> 16) & 1u)) >> 16);
}

// ---------------- K0a: h = key @ wh_w.T + wh_b  (64 x 512) ----------------
__global__ void k_h(const float* __restrict__ key, const float* __restrict__ wh_w,
                    const float* __restrict__ wh_b, float* __restrict__ h) {
    const int b = blockIdx.y;
    const int ac = blockIdx.x;
    const int t = threadIdx.x;         // 256
    const int lane = t & 63, wv = t >> 6;
    float k16[16];
    const float* kb = key + b * HIDSZ;
#pragma unroll
    for (int j = 0; j < 16; ++j) k16[j] = kb[lane + 64 * j];
#pragma unroll 1
    for (int i = 0; i < 16; ++i) {
        int a = ac * 64 + wv * 16 + i;
        const float* wr = wh_w + (size_t)a * HIDSZ;
        float s = 0.f;
#pragma unroll
        for (int j = 0; j < 16; ++j) s += k16[j] * wr[lane + 64 * j];
#pragma unroll
        for (int d = 32; d; d >>= 1) s += __shfl_xor(s, d);
        if (lane == 0) h[b * ATTSZ + a] = s + wh_b[a];
    }
}

// ------- K0b: convert wv_w (512x2048 f32) -> bf16 in MFMA-fragment order -------
__global__ void k_wvcvt(const float* __restrict__ wv_w, unsigned short* __restrict__ wvb) {
    int idx = blockIdx.x * 256 + threadIdx.x;       // < 512*2048
    int a = idx >> 11, k = idx & 2047;
    int CF = a >> 4, c = a & 15, ks = k >> 5, kin = k & 31;
    int lane = c + ((kin >> 3) << 4);
    int dst = ((ks * 32 + CF) * 64 + lane) * 8 + (kin & 7);
    wvb[dst] = f2bf(wv_w[idx]);
}

// ---------------- K1: fused GEMM(feats, wv^T) + tanh·wa -> partial scores -------
// Faithful m201 rhythm: 256 blocks (1/CU), 512 thr = 8 waves (2M x 4N).
// BM=256 x BN=256 (nt) x BK=64, 32 K-tiles x 4 phases; EACH phase =
// {4 ds_read_b128 + staggered staging issue; BAR; lgkmcnt(0); 16 MFMA; BAR}.
// A: fp32 glb->named FH/SH regs (2-3-phase cover) -> bf16 -> swizzled ds_write.
// B: L2-resident frag-ordered wvb, BX/BY ping-pong loaded 2 phases ahead.
__global__ __launch_bounds__(512) void k_scores(
        const float* __restrict__ feats, const unsigned short* __restrict__ wvb,
        const float* __restrict__ h, const float* __restrict__ wv_b,
        const float* __restrict__ wa, float* __restrict__ part_sc) {
    __shared__ __align__(16) char Abuf[2][32768];   // [buf][256 rows][64 k] bf16 swizzled
    __shared__ float scp[4][256];
    const int t = threadIdx.x, lane = t & 63, w = t >> 6;
    const int wm = w >> 2, wn = w & 3;
    const int mb = blockIdx.x >> 1, nt = blockIdx.x & 1;
    const int m0 = mb * 256, b = blockIdx.x >> 2;

    // ---- staging map: thread -> row sr = t>>1, k-half sh = t&1 (32 k each)
    const int sr = t >> 1, sh = t & 1;
    const float* gbase = feats + (size_t)(m0 + sr) * FEATSZ + sh * 32;
    int wq[4];
#pragma unroll
    for (int q = 0; q < 4; ++q)
        wq[q] = sr * 128 + (((sh * 4 + q) ^ (sr & 7)) * 16);

    // ---- B base: CF = nt*16 + wn*4 + cf
    const unsigned short* wbase = wvb + (size_t)(nt * 16 + wn * 4) * 512 + lane * 8;

    // ---- A-frag read consts (R11 layout: measured 0 conflicts)
    const int arow = wm * 128 + (lane & 15);
    const int aq = lane >> 4, ax = lane & 7;

    f32x4 acc[8][4];
#pragma unroll
    for (int m = 0; m < 8; ++m)
#pragma unroll
        for (int cf = 0; cf < 4; ++cf) acc[m][cf] = (f32x4)0.0f;

    bf16x8 BX[4], BY[4];
    f32x4 FH0, FH1, FH2, FH3, SH0, SH1, SH2, SH3;   // named staging regs

    auto ldG = [&](int kt, int i) -> f32x4 {
        return *(const f32x4*)(gbase + kt * 64 + i * 4);
    };
    auto loadB = [&](bf16x8(&B)[4], int kkg) {
#pragma unroll
        for (int cf = 0; cf < 4; ++cf)
            B[cf] = *(const bf16x8*)(wbase + (size_t)(kkg * 32 + cf) * 512);
    };
    auto cvtW = [&](char* bw, int q, f32x4 a, f32x4 c) {
        bf16x8 v;
        v[0] = (__bf16)a[0]; v[1] = (__bf16)a[1]; v[2] = (__bf16)a[2]; v[3] = (__bf16)a[3];
        v[4] = (__bf16)c[0]; v[5] = (__bf16)c[1]; v[6] = (__bf16)c[2]; v[7] = (__bf16)c[3];
        *(bf16x8*)__builtin_assume_aligned(bw + wq[q], 16) = v;
    };
    auto dsr4 = [&](const char* br, int mg, int kk, bf16x8(&A)[4]) {
#pragma unroll
        for (int i = 0; i < 4; ++i)
            A[i] = *(const bf16x8*)__builtin_assume_aligned(
                br + (arow + (mg + i) * 16) * 128 + (((kk * 4 + aq) ^ ax) * 16), 16);
    };
    auto mfma16 = [&](int mg, bf16x8(&A)[4], bf16x8(&B)[4]) {
        __builtin_amdgcn_s_setprio(1);
#pragma unroll
        for (int m = 0; m < 4; ++m)
#pragma unroll
            for (int cf = 0; cf < 4; ++cf)
                acc[mg + m][cf] = __builtin_amdgcn_mfma_f32_16x16x32_bf16(A[m], B[cf], acc[mg + m][cf], 0, 0, 0);
        __builtin_amdgcn_s_setprio(0);
    };
    auto barIssue = [&]() {            // end of issue cluster -> BAR1 -> lgkm0
        __builtin_amdgcn_sched_barrier(0);
        __builtin_amdgcn_s_barrier();
        asm volatile("s_waitcnt lgkmcnt(0)" ::: "memory");
        __builtin_amdgcn_sched_barrier(0);
    };

    // ---- prologue: tile 0 staged to buf0; FH <- tile1 first half; BX(0,kk0)
    FH0 = ldG(0, 0); FH1 = ldG(0, 1); FH2 = ldG(0, 2); FH3 = ldG(0, 3);
    SH0 = ldG(0, 4); SH1 = ldG(0, 5); SH2 = ldG(0, 6); SH3 = ldG(0, 7);
    loadB(BX, 0);
    cvtW(&Abuf[0][0], 0, FH0, FH1); cvtW(&Abuf[0][0], 1, FH2, FH3);
    cvtW(&Abuf[0][0], 2, SH0, SH1); cvtW(&Abuf[0][0], 3, SH2, SH3);
    FH0 = ldG(1, 0); FH1 = ldG(1, 1); FH2 = ldG(1, 2); FH3 = ldG(1, 3);
    asm volatile("s_waitcnt lgkmcnt(0)" ::: "memory");
    __builtin_amdgcn_s_barrier();

#pragma unroll 1
    for (int kt = 0; kt < 32; ++kt) {
        const char* br = &Abuf[kt & 1][0];
        char* bw = &Abuf[(kt & 1) ^ 1][0];
        bf16x8 A0[4], A1[4], A2[4], A3[4];
        // ---- phase 0: frags m0-3/kk0; SH<-(kt+1) loads 4,5; BY<-(kt,kk1)
        dsr4(br, 0, 0, A0);
        if (kt < 31) { SH0 = ldG(kt + 1, 4); SH1 = ldG(kt + 1, 5); }
        loadB(BY, kt * 2 + 1);
        barIssue();
        mfma16(0, A0, BX);
        __builtin_amdgcn_s_barrier();
        // ---- phase 1: frags m4-7/kk0; write Q0,Q1(kt+1) from FH; SH loads 6,7
        dsr4(br, 4, 0, A1);
        if (kt < 31) {
            cvtW(bw, 0, FH0, FH1); cvtW(bw, 1, FH2, FH3);
            SH2 = ldG(kt + 1, 6); SH3 = ldG(kt + 1, 7);
        }
        barIssue();
        mfma16(4, A1, BX);
        __builtin_amdgcn_s_barrier();
        // ---- phase 2: frags m0-3/kk1; FH<-(kt+2) loads 0,1; BX<-(kt+1,kk0)
        dsr4(br, 0, 1, A2);
        if (kt < 30) { FH0 = ldG(kt + 2, 0); FH1 = ldG(kt + 2, 1); }
        if (kt < 31) loadB(BX, (kt + 1) * 2);
        barIssue();
        mfma16(0, A2, BY);
        __builtin_amdgcn_s_barrier();
        // ---- phase 3: frags m4-7/kk1; write Q2,Q3(kt+1) from SH; FH loads 2,3
        dsr4(br, 4, 1, A3);
        if (kt < 31) { cvtW(bw, 2, SH0, SH1); cvtW(bw, 3, SH2, SH3); }
        if (kt < 30) { FH2 = ldG(kt + 2, 2); FH3 = ldG(kt + 2, 3); }
        barIssue();
        mfma16(4, A3, BY);
        __builtin_amdgcn_s_barrier();
    }

    // ---- epilogue: partial score over this block's 256 cols
    const int c16 = lane & 15, q4 = lane >> 4;
    float hreg[4], wreg[4];
#pragma unroll
    for (int cf = 0; cf < 4; ++cf) {
        int a = nt * 256 + wn * 64 + cf * 16 + c16;
        hreg[cf] = h[b * ATTSZ + a] + wv_b[a];
        wreg[cf] = wa[a];
    }
    float pv[8][4];
#pragma unroll
    for (int m = 0; m < 8; ++m)
#pragma unroll
        for (int jr = 0; jr < 4; ++jr) pv[m][jr] = 0.f;
#pragma unroll
    for (int m = 0; m < 8; ++m)
#pragma unroll
        for (int cf = 0; cf < 4; ++cf)
#pragma unroll
            for (int jr = 0; jr < 4; ++jr)
                pv[m][jr] += tanhf(acc[m][cf][jr] + hreg[cf]) * wreg[cf];
#pragma unroll
    for (int m = 0; m < 8; ++m)
#pragma unroll
        for (int jr = 0; jr < 4; ++jr) {
            float v = pv[m][jr];
            v += __shfl_xor(v, 1); v += __shfl_xor(v, 2);
            v += __shfl_xor(v, 4); v += __shfl_xor(v, 8);
            pv[m][jr] = v;
        }
    if (c16 == 0) {
#pragma unroll
        for (int m = 0; m < 8; ++m)
#pragma unroll
            for (int jr = 0; jr < 4; ++jr)
                scp[wn][wm * 128 + m * 16 + q4 * 4 + jr] = pv[m][jr];
    }
    __syncthreads();
    if (t < 256)
        part_sc[nt * (BATCH * FEATN) + m0 + t]
            = scp[0][t] + scp[1][t] + scp[2][t] + scp[3][t];
}

// ---------------- K2: softmax over N=512 per batch (sums 2 col-partials) --------
__global__ void k_softmax(const float* __restrict__ part_sc, float* __restrict__ alpha) {
    __shared__ float red[16];
    const int b = blockIdx.x, t = threadIdx.x;     // 512 threads
    const int lane = t & 63, w = t >> 6;
    const int r = b * FEATN + t;
    float s = part_sc[r] + part_sc[BATCH * FEATN + r];
    float m = s;
#pragma unroll
    for (int d = 32; d; d >>= 1) m = fmaxf(m, __shfl_xor(m, d));
    if (lane == 0) red[w] = m;
    __syncthreads();
    if (t == 0) {
        float mm = red[0];
        for (int i = 1; i < 8; ++i) mm = fmaxf(mm, red[i]);
        red[8] = mm;
    }
    __syncthreads();
    float e = __expf(s - red[8]);
    float sum = e;
#pragma unroll
    for (int d = 32; d; d >>= 1) sum += __shfl_xor(sum, d);
    if (lane == 0) red[w] = sum;
    __syncthreads();
    if (t == 0) {
        float ss = 0.f;
        for (int i = 0; i < 8; ++i) ss += red[i];
        red[9] = 1.0f / ss;
    }
    __syncthreads();
    alpha[b * FEATN + t] = e * red[9];
}

// ---------------- K3a: partial att_feats over n-slices ----------------
__global__ void k_att_part(const float* __restrict__ feats, const float* __restrict__ alpha,
                           float* __restrict__ part) {
    const int b = blockIdx.x, fc = blockIdx.y, ns = blockIdx.z, t = threadIdx.x;
    const int f0 = fc * 1024 + t * 4;
    const float* fp = feats + (size_t)(b * FEATN + ns * 128) * FEATSZ + f0;
    const float* al = alpha + b * FEATN + ns * 128;
    float4 acc = {0.f, 0.f, 0.f, 0.f};
#pragma unroll 4
    for (int i = 0; i < 128; ++i) {
        float a = al[i];
        float4 v = *(const float4*)(fp + (size_t)i * FEATSZ);
        acc.x += a * v.x; acc.y += a * v.y; acc.z += a * v.z; acc.w += a * v.w;
    }
    *(float4*)(part + ((size_t)ns * BATCH + b) * FEATSZ + f0) = acc;
}

// ---------------- K3b: reduce 4 partials -> att_feats ----------------
__global__ void k_att_red(const float* __restrict__ part, float* __restrict__ out) {
    const int idx = (blockIdx.x * 256 + threadIdx.x) * 4;   // < 131072
    float4 s = *(const float4*)(part + idx);
#pragma unroll
    for (int z = 1; z < 4; ++z) {
        float4 v = *(const float4*)(part + (size_t)z * (BATCH * FEATSZ) + idx);
        s.x += v.x; s.y += v.y; s.z += v.z; s.w += v.w;
    }
    *(float4*)(out + idx) = s;
}

extern "C" void kernel_launch(void* const* d_in, const int* in_sizes, int n_in,
                              void* d_out, int out_size, void* d_ws, size_t ws_size,
                              hipStream_t stream) {
    const float* feats = (const float*)d_in[0];
    const float* key   = (const float*)d_in[1];
    const float* wh_w  = (const float*)d_in[2];
    const float* wh_b  = (const float*)d_in[3];
    const float* wv_w  = (const float*)d_in[4];
    const float* wv_b  = (const float*)d_in[5];
    const float* wa_w  = (const float*)d_in[6];

    float* out_att   = (float*)d_out;                 // 64*2048
    float* out_alpha = out_att + BATCH * FEATSZ;      // 64*512

    char* ws = (char*)d_ws;
    float* h            = (float*)(ws);               // 128 KB
    float* part_sc      = (float*)(ws + 131072);      // 2 x 128 KB
    unsigned short* wvb = (unsigned short*)(ws + 393216);  // 2 MB
    float* part         = (float*)(ws + 393216);      // 2 MB (reuses wvb after K1)

    hipLaunchKernelGGL(k_h,        dim3(8, 64),    dim3(256), 0, stream, key, wh_w, wh_b, h);
    hipLaunchKernelGGL(k_wvcvt,    dim3(4096),     dim3(256), 0, stream, wv_w, wvb);
    hipLaunchKernelGGL(k_scores,   dim3(256),      dim3(512), 0, stream, feats, wvb, h, wv_b, wa_w, part_sc);
    hipLaunchKernelGGL(k_softmax,  dim3(64),       dim3(512), 0, stream, part_sc, out_alpha);
    hipLaunchKernelGGL(k_att_part, dim3(64, 2, 4), dim3(256), 0, stream, feats, out_alpha, part);
    hipLaunchKernelGGL(k_att_red,  dim3(128),      dim3(256), 0, stream, part, out_att);
}

// Round 13
// 213.843 us; speedup vs baseline: 1.4877x; 1.4877x over previous
//
#include <hip/hip_runtime.h>
#include <hip/hip_bf16.h>

#define FEATSZ 2048
#define HIDSZ  1024
#define ATTSZ  512
#define BATCH  64
#define FEATN  512

typedef float  f32x4  __attribute__((ext_vector_type(4)));
typedef __bf16 bf16x8 __attribute__((ext_vector_type(8)));

__device__ __forceinline__ unsigned short f2bf(float f) {
    union { float f; unsigned int u; } x; x.f = f;
    unsigned int u = x.u;
    return (unsigned short)((u + 0x7fffu + ((u >> 16) & 1u)) >> 16);
}

// ---------------- K0a: h = key @ wh_w.T + wh_b  (64 x 512) ----------------
__global__ void k_h(const float* __restrict__ key, const float* __restrict__ wh_w,
                    const float* __restrict__ wh_b, float* __restrict__ h) {
    const int b = blockIdx.y;
    const int ac = blockIdx.x;
    const int t = threadIdx.x;         // 256
    const int lane = t & 63, wv = t >> 6;
    float k16[16];
    const float* kb = key + b * HIDSZ;
#pragma unroll
    for (int j = 0; j < 16; ++j) k16[j] = kb[lane + 64 * j];
#pragma unroll 1
    for (int i = 0; i < 16; ++i) {
        int a = ac * 64 + wv * 16 + i;
        const float* wr = wh_w + (size_t)a * HIDSZ;
        float s = 0.f;
#pragma unroll
        for (int j = 0; j < 16; ++j) s += k16[j] * wr[lane + 64 * j];
#pragma unroll
        for (int d = 32; d; d >>= 1) s += __shfl_xor(s, d);
        if (lane == 0) h[b * ATTSZ + a] = s + wh_b[a];
    }
}

// ------- K0b: convert wv_w (512x2048 f32) -> bf16 in MFMA-fragment order -------
// frag (kk, CF) = 1024B at (kk*32+CF)*1024; lane l holds 16B (8 bf16) at +l*16.
__global__ void k_wvcvt(const float* __restrict__ wv_w, unsigned short* __restrict__ wvb) {
    int idx = blockIdx.x * 256 + threadIdx.x;       // < 512*2048
    int a = idx >> 11, k = idx & 2047;
    int CF = a >> 4, c = a & 15, ks = k >> 5, kin = k & 31;
    int lane = c + ((kin >> 3) << 4);
    int dst = ((ks * 32 + CF) * 64 + lane) * 8 + (kin & 7);
    wvb[dst] = f2bf(wv_w[idx]);
}

// ---------------- K1: fused GEMM(feats, wv^T) + tanh·wa -> scores ----------------
// Occupancy + economy: 512 blocks (2/CU -> 16 waves/CU from INDEPENDENT blocks),
// 512 thr = 8 waves. BM=64 (feats read once) x BN=512 x BK=32, 64 steps.
// Wave = 64 rows x 64 cols: acc = 64 VGPR. A: fp32 glb->reg (issued at step top,
// 1-step cover) -> bf16 cvt ONCE -> swizzled ds_write (R10 layout: 0 conflicts).
// B: L2-resident frag-ordered wvb, 1-step reg ping-pong (named BX/BY, x2 unroll).
// ONE lgkmcnt(0)+s_barrier per step (dbuf write-other-read-cur needs only one).
__global__ __launch_bounds__(512, 4) void k_scores(
        const float* __restrict__ feats, const unsigned short* __restrict__ wvb,
        const float* __restrict__ h, const float* __restrict__ wv_b,
        const float* __restrict__ wa, float* __restrict__ scores) {
    __shared__ __align__(16) char Abuf[2][4096];   // [buf][64 rows][32 k] bf16 swizzled
    __shared__ float scp[8][64];
    const int t = threadIdx.x, lane = t & 63, w = t >> 6;
    const int m0 = blockIdx.x * 64, b = blockIdx.x >> 3;

    // ---- staging (threads 0-255): row = t>>2, 16B-chunk sq = t&3 (8 bf16 = 8 fp32)
    const int srow = t >> 2, sq = t & 3;
    const float* gsrc = feats + (size_t)(m0 + srow) * FEATSZ + sq * 8;
    const int wboff = srow * 64 + ((sq ^ ((srow >> 1) & 3)) * 16);
    const bool stager = (t < 256);

    // ---- A frag read: frag m: row = m*16 + (lane&15), chunk q = lane>>4,
    //      phys = q ^ (((lane&15)>>1)&3)  (R10 mapping, measured 0 conflicts)
    const int rbase = (lane & 15) * 64 + (((lane >> 4) ^ (((lane & 15) >> 1) & 3)) * 16);

    // ---- B: wave w covers cols w*64.. -> CF = w*4+cf; frag (kk,CF) at (kk*32+CF)*512
    const unsigned short* wb = wvb + (size_t)(w * 4) * 512 + lane * 8;

    f32x4 acc[4][4];
#pragma unroll
    for (int m = 0; m < 4; ++m)
#pragma unroll
        for (int cf = 0; cf < 4; ++cf) acc[m][cf] = (f32x4)0.0f;

    bf16x8 BX[4], BY[4];
    auto loadBX = [&](int kk) {
#pragma unroll
        for (int cf = 0; cf < 4; ++cf) BX[cf] = *(const bf16x8*)(wb + (size_t)(kk * 32 + cf) * 512);
    };
    auto loadBY = [&](int kk) {
#pragma unroll
        for (int cf = 0; cf < 4; ++cf) BY[cf] = *(const bf16x8*)(wb + (size_t)(kk * 32 + cf) * 512);
    };
    auto cvtWrite = [&](int buf, f32x4 u0, f32x4 u1) {
        if (stager) {
            bf16x8 v;
            v[0] = (__bf16)u0[0]; v[1] = (__bf16)u0[1]; v[2] = (__bf16)u0[2]; v[3] = (__bf16)u0[3];
            v[4] = (__bf16)u1[0]; v[5] = (__bf16)u1[1]; v[6] = (__bf16)u1[2]; v[7] = (__bf16)u1[3];
            *(bf16x8*)__builtin_assume_aligned(&Abuf[buf][0] + wboff, 16) = v;
        }
    };
    auto mfma16 = [&](int buf, bf16x8(&B)[4]) {
        const char* ab = &Abuf[buf][0];
        bf16x8 a0 = *(const bf16x8*)__builtin_assume_aligned(ab + 0 * 1024 + rbase, 16);
        bf16x8 a1 = *(const bf16x8*)__builtin_assume_aligned(ab + 1 * 1024 + rbase, 16);
        bf16x8 a2 = *(const bf16x8*)__builtin_assume_aligned(ab + 2 * 1024 + rbase, 16);
        bf16x8 a3 = *(const bf16x8*)__builtin_assume_aligned(ab + 3 * 1024 + rbase, 16);
        __builtin_amdgcn_s_setprio(1);
#pragma unroll
        for (int cf = 0; cf < 4; ++cf) acc[0][cf] = __builtin_amdgcn_mfma_f32_16x16x32_bf16(a0, B[cf], acc[0][cf], 0, 0, 0);
#pragma unroll
        for (int cf = 0; cf < 4; ++cf) acc[1][cf] = __builtin_amdgcn_mfma_f32_16x16x32_bf16(a1, B[cf], acc[1][cf], 0, 0, 0);
#pragma unroll
        for (int cf = 0; cf < 4; ++cf) acc[2][cf] = __builtin_amdgcn_mfma_f32_16x16x32_bf16(a2, B[cf], acc[2][cf], 0, 0, 0);
#pragma unroll
        for (int cf = 0; cf < 4; ++cf) acc[3][cf] = __builtin_amdgcn_mfma_f32_16x16x32_bf16(a3, B[cf], acc[3][cf], 0, 0, 0);
        __builtin_amdgcn_s_setprio(0);
    };
    auto bar = [&]() {
        asm volatile("s_waitcnt lgkmcnt(0)" ::: "memory");
        __builtin_amdgcn_s_barrier();
        __builtin_amdgcn_sched_barrier(0);
    };

    // ---- prologue: tile 0 -> buf0; BX <- B(0)
    {
        f32x4 u0, u1;
        if (stager) {
            u0 = *(const f32x4*)gsrc;
            u1 = *(const f32x4*)(gsrc + 4);
        }
        loadBX(0);
        cvtWrite(0, u0, u1);
        bar();
    }

#pragma unroll 1
    for (int jj = 0; jj < 32; ++jj) {
        const int j = jj * 2;
        // ---- even step j: compute buf[0] with BX; stage tile j+1 -> buf1; BY <- B(j+1)
        {
            f32x4 u0, u1;
            if (stager && j < 63) {
                const float* p = gsrc + (j + 1) * 32;
                u0 = *(const f32x4*)p; u1 = *(const f32x4*)(p + 4);
            }
            if (j < 63) loadBY(j + 1);
            mfma16(0, BX);
            if (j < 63) cvtWrite(1, u0, u1);
            bar();
        }
        // ---- odd step j+1: compute buf[1] with BY; stage tile j+2 -> buf0; BX <- B(j+2)
        {
            f32x4 u0, u1;
            if (stager && j < 62) {
                const float* p = gsrc + (j + 2) * 32;
                u0 = *(const f32x4*)p; u1 = *(const f32x4*)(p + 4);
            }
            if (j < 62) loadBX(j + 2);
            mfma16(1, BY);
            if (j < 62) cvtWrite(0, u0, u1);
            bar();
        }
    }

    // ---- epilogue: score[row] = sum_a tanh(acc + h[b,a] + wv_b[a]) * wa[a]
    const int c16 = lane & 15, q4 = lane >> 4;
    float hreg[4], wreg[4];
#pragma unroll
    for (int cf = 0; cf < 4; ++cf) {
        int a = w * 64 + cf * 16 + c16;
        hreg[cf] = h[b * ATTSZ + a] + wv_b[a];
        wreg[cf] = wa[a];
    }
    float pv[4][4];
#pragma unroll
    for (int m = 0; m < 4; ++m)
#pragma unroll
        for (int jr = 0; jr < 4; ++jr) pv[m][jr] = 0.f;
#pragma unroll
    for (int m = 0; m < 4; ++m)
#pragma unroll
        for (int cf = 0; cf < 4; ++cf)
#pragma unroll
            for (int jr = 0; jr < 4; ++jr)
                pv[m][jr] += tanhf(acc[m][cf][jr] + hreg[cf]) * wreg[cf];
#pragma unroll
    for (int m = 0; m < 4; ++m)
#pragma unroll
        for (int jr = 0; jr < 4; ++jr) {
            float v = pv[m][jr];
            v += __shfl_xor(v, 1); v += __shfl_xor(v, 2);
            v += __shfl_xor(v, 4); v += __shfl_xor(v, 8);
            pv[m][jr] = v;
        }
    if (c16 == 0) {
#pragma unroll
        for (int m = 0; m < 4; ++m)
#pragma unroll
            for (int jr = 0; jr < 4; ++jr)
                scp[w][m * 16 + q4 * 4 + jr] = pv[m][jr];
    }
    __syncthreads();
    if (t < 64) {
        float s = 0.f;
#pragma unroll
        for (int ww = 0; ww < 8; ++ww) s += scp[ww][t];
        scores[m0 + t] = s;
    }
}

// ---------------- K2: softmax over N=512 per batch ----------------
__global__ void k_softmax(const float* __restrict__ scores, float* __restrict__ alpha) {
    __shared__ float red[16];
    const int b = blockIdx.x, t = threadIdx.x;     // 512 threads
    const int lane = t & 63, w = t >> 6;
    float s = scores[b * FEATN + t];
    float m = s;
#pragma unroll
    for (int d = 32; d; d >>= 1) m = fmaxf(m, __shfl_xor(m, d));
    if (lane == 0) red[w] = m;
    __syncthreads();
    if (t == 0) {
        float mm = red[0];
        for (int i = 1; i < 8; ++i) mm = fmaxf(mm, red[i]);
        red[8] = mm;
    }
    __syncthreads();
    float e = __expf(s - red[8]);
    float sum = e;
#pragma unroll
    for (int d = 32; d; d >>= 1) sum += __shfl_xor(sum, d);
    if (lane == 0) red[w] = sum;
    __syncthreads();
    if (t == 0) {
        float ss = 0.f;
        for (int i = 0; i < 8; ++i) ss += red[i];
        red[9] = 1.0f / ss;
    }
    __syncthreads();
    alpha[b * FEATN + t] = e * red[9];
}

// ---------------- K3a: partial att_feats over n-slices ----------------
__global__ void k_att_part(const float* __restrict__ feats, const float* __restrict__ alpha,
                           float* __restrict__ part) {
    const int b = blockIdx.x, fc = blockIdx.y, ns = blockIdx.z, t = threadIdx.x;
    const int f0 = fc * 1024 + t * 4;
    const float* fp = feats + (size_t)(b * FEATN + ns * 128) * FEATSZ + f0;
    const float* al = alpha + b * FEATN + ns * 128;
    float4 acc = {0.f, 0.f, 0.f, 0.f};
#pragma unroll 4
    for (int i = 0; i < 128; ++i) {
        float a = al[i];
        float4 v = *(const float4*)(fp + (size_t)i * FEATSZ);
        acc.x += a * v.x; acc.y += a * v.y; acc.z += a * v.z; acc.w += a * v.w;
    }
    *(float4*)(part + ((size_t)ns * BATCH + b) * FEATSZ + f0) = acc;
}

// ---------------- K3b: reduce 4 partials -> att_feats ----------------
__global__ void k_att_red(const float* __restrict__ part, float* __restrict__ out) {
    const int idx = (blockIdx.x * 256 + threadIdx.x) * 4;   // < 131072
    float4 s = *(const float4*)(part + idx);
#pragma unroll
    for (int z = 1; z < 4; ++z) {
        float4 v = *(const float4*)(part + (size_t)z * (BATCH * FEATSZ) + idx);
        s.x += v.x; s.y += v.y; s.z += v.z; s.w += v.w;
    }
    *(float4*)(out + idx) = s;
}

extern "C" void kernel_launch(void* const* d_in, const int* in_sizes, int n_in,
                              void* d_out, int out_size, void* d_ws, size_t ws_size,
                              hipStream_t stream) {
    const float* feats = (const float*)d_in[0];
    const float* key   = (const float*)d_in[1];
    const float* wh_w  = (const float*)d_in[2];
    const float* wh_b  = (const float*)d_in[3];
    const float* wv_w  = (const float*)d_in[4];
    const float* wv_b  = (const float*)d_in[5];
    const float* wa_w  = (const float*)d_in[6];

    float* out_att   = (float*)d_out;                 // 64*2048
    float* out_alpha = out_att + BATCH * FEATSZ;      // 64*512

    char* ws = (char*)d_ws;
    float* h            = (float*)(ws);               // 128 KB
    float* scores       = (float*)(ws + 131072);      // 128 KB
    unsigned short* wvb = (unsigned short*)(ws + 262144);  // 2 MB
    float* part         = (float*)(ws + 262144);      // 2 MB (reuses wvb after K1)

    hipLaunchKernelGGL(k_h,        dim3(8, 64),    dim3(256), 0, stream, key, wh_w, wh_b, h);
    hipLaunchKernelGGL(k_wvcvt,    dim3(4096),     dim3(256), 0, stream, wv_w, wvb);
    hipLaunchKernelGGL(k_scores,   dim3(512),      dim3(512), 0, stream, feats, wvb, h, wv_b, wa_w, scores);
    hipLaunchKernelGGL(k_softmax,  dim3(64),       dim3(512), 0, stream, scores, out_alpha);
    hipLaunchKernelGGL(k_att_part, dim3(64, 2, 4), dim3(256), 0, stream, feats, out_alpha, part);
    hipLaunchKernelGGL(k_att_red,  dim3(128),      dim3(256), 0, stream, part, out_att);
}